// Round 4
// baseline (416.185 us; speedup 1.0000x reference)
//
#include <hip/hip_runtime.h>
#include <hip/hip_bf16.h>
#include <stdint.h>

#define M_ROWS 4096
#define N_REFS 32768
#define DIM    512
#define NSPLIT 32
#define BM     128
#define CHUNK  128
#define SLICE  (N_REFS / NSPLIT)   // 1024
#define NCHUNKS (SLICE / CHUNK)    // 8

typedef __attribute__((ext_vector_type(8))) short short8;
typedef __attribute__((ext_vector_type(4))) float f32x4;

__device__ __forceinline__ uint32_t f2bf1(float f) {
  uint32_t u = __float_as_uint(f);
  return (u + 0x7FFFu + ((u >> 16) & 1u)) >> 16;   // RNE fp32 -> bf16
}

// One block per row: convert fp32 row -> bf16 (packed), compute sum of squares in fp32.
__global__ void prep_rows(const float* __restrict__ src, uint16_t* __restrict__ dst,
                          float* __restrict__ sq) {
  int row = blockIdx.x;
  int t = threadIdx.x;                       // 256 threads, 2 elems each
  const float2* s = (const float2*)(src + (size_t)row * DIM);
  float2 v = s[t];
  uint32_t packed = f2bf1(v.x) | (f2bf1(v.y) << 16);
  ((uint32_t*)(dst + (size_t)row * DIM))[t] = packed;
  float ss = v.x * v.x + v.y * v.y;
  #pragma unroll
  for (int d = 32; d >= 1; d >>= 1) ss += __shfl_down(ss, d, 64);
  __shared__ float wsum[4];
  int w = t >> 6, lane = t & 63;
  if (lane == 0) wsum[w] = ss;
  __syncthreads();
  if (t == 0) sq[row] = wsum[0] + wsum[1] + wsum[2] + wsum[3];
}

// Chunk body: K-loop (8 x BK=64) accumulating into `cur`, with the epilogue of the
// PREVIOUS chunk (`prv`, metadata r2cP/clsP) spread 2-of-16 row-groups per kk step,
// inside the ds_read+MFMA basic block so it schedules into the MFMA shadow (T15).
template<bool HP>
__device__ __forceinline__ void chunk_body(
    f32x4 (&cur)[4][4], f32x4 (&prv)[4][4],
    int colb,
    const uint16_t* __restrict__ rbf, const uint16_t* __restrict__ gA0,
    unsigned char* sA, unsigned char* sB,
    const int (&aoff)[4], const int (&boff)[4],
    int srow, int scol, int w, int wc, int l15,
    const float* __restrict__ r2, const int* __restrict__ yref,
    float (&r2cP)[4], int (&clsP)[4],
    const float (&x2v)[16], const int (&yv)[16],
    float (&tot)[16], float (&mat)[16])
{
  const uint16_t* gB0 = rbf + (size_t)(colb + srow) * DIM + scol;

  // current chunk's column metadata (becomes prev at the end)
  float r2cC[4]; int clsC[4];
  #pragma unroll
  for (int ni = 0; ni < 4; ++ni) {
    int c = colb + wc * 64 + ni * 16 + l15;
    r2cC[ni] = r2[c];
    clsC[ni] = yref[c];
  }

  const f32x4 fzero = {0.f, 0.f, 0.f, 0.f};
  #pragma unroll
  for (int mi = 0; mi < 4; ++mi)
    #pragma unroll
    for (int ni = 0; ni < 4; ++ni)
      cur[mi][ni] = fzero;

  #pragma unroll
  for (int kk = 0; kk < 8; ++kk) {
    const int dk = kk * 64;
    #pragma unroll
    for (int c = 0; c < 4; ++c) {
      __builtin_amdgcn_global_load_lds(
          (const __attribute__((address_space(1))) void*)(gA0 + (size_t)c * 32 * DIM + dk),
          (__attribute__((address_space(3))) void*)(sA + c * 4096 + w * 1024),
          16, 0, 0);
    }
    #pragma unroll
    for (int c = 0; c < 4; ++c) {
      __builtin_amdgcn_global_load_lds(
          (const __attribute__((address_space(1))) void*)(gB0 + (size_t)c * 32 * DIM + dk),
          (__attribute__((address_space(3))) void*)(sB + c * 4096 + w * 1024),
          16, 0, 0);
    }
    __syncthreads();

    #pragma unroll
    for (int sk = 0; sk < 2; ++sk) {
      short8 af[4], bf[4];
      #pragma unroll
      for (int i = 0; i < 4; ++i) af[i] = *(const short8*)(sA + (aoff[i] ^ (sk << 6)));
      #pragma unroll
      for (int i = 0; i < 4; ++i) bf[i] = *(const short8*)(sB + (boff[i] ^ (sk << 6)));
      #pragma unroll
      for (int mi = 0; mi < 4; ++mi)
        #pragma unroll
        for (int ni = 0; ni < 4; ++ni)
          cur[mi][ni] = __builtin_amdgcn_mfma_f32_16x16x32_bf16(af[mi], bf[ni], cur[mi][ni], 0, 0, 0);
    }

    if (HP) {
      // epilogue of prev chunk: groups g = 2*kk, 2*kk+1 (static — kk is unrolled)
      #pragma unroll
      for (int j = 0; j < 2; ++j) {
        const int g  = kk * 2 + j;
        const int mi = g >> 2, rr = g & 3;
        float xr = x2v[g];
        int   yy = yv[g];
        float tsum = 0.f, msum = 0.f;
        #pragma unroll
        for (int ni = 0; ni < 4; ++ni) {
          float t = fmaf(-2.0f, prv[mi][ni][rr], xr + r2cP[ni]);
          t = fmaxf(t, 0.0f);
          float d = __builtin_amdgcn_sqrtf(t);
          float e = __builtin_amdgcn_exp2f(-1.44269504088896f * d);
          tsum += e;
          msum += (clsP[ni] == yy) ? e : 0.0f;
        }
        tot[g] += tsum;
        mat[g] += msum;
      }
    }

    __syncthreads();
  }

  // rotate metadata: current becomes prev
  #pragma unroll
  for (int ni = 0; ni < 4; ++ni) { r2cP[ni] = r2cC[ni]; clsP[ni] = clsC[ni]; }
}

// Main fused kernel: 128x128 output tile, BK=64, 4 waves (2x2), 4x4 16x16x32 MFMA per wave.
// No-max softmax: scores in [-40,-21] are fp32-safe as raw exp. Accumulate per-row
// total and matching-class sums; merge across blocks with atomicAdd.
// NOTE: (256,2) — (256,4) capped VGPR at 128 total and spilled the accumulators
// (R2: WRITE_SIZE 4->397MB). We are pinned at 2 waves/SIMD anyway, so the second
// acc buffer for the chunk pipeline is "free" register headroom.
__global__ __launch_bounds__(256, 2) void ask_main(
    const uint16_t* __restrict__ xbf, const uint16_t* __restrict__ rbf,
    const float* __restrict__ x2, const float* __restrict__ r2,
    const int* __restrict__ y, const int* __restrict__ yref,
    float* __restrict__ totG, float* __restrict__ matchG)
{
  __shared__ unsigned char smem[32768];      // A tile 16KB | B tile 16KB
  unsigned char* sA = smem;
  unsigned char* sB = smem + 16384;

  const int tid  = threadIdx.x;
  const int w    = tid >> 6, lane = tid & 63;
  const int wr   = w >> 1,  wc   = w & 1;
  const int l15  = lane & 15, l4 = lane >> 4;

  const int bm       = blockIdx.x * BM;
  const int colstart = blockIdx.y * SLICE;

  // global_load_lds staging: LDS is linear [128][64] bf16 (128B rows); the XOR
  // swizzle ((row&7)<<4) is applied by permuting the *global source* column.
  const int srow = w * 8 + (lane >> 3);                       // 0..31 per call
  const int scol = ((lane & 7) ^ ((lane >> 3) & 7)) * 8;      // pre-swizzled col
  const uint16_t* gA0 = xbf + (size_t)(bm + srow) * DIM + scol;

  // fragment read offsets (swizzled): addr = row*128 + ((16*l4) ^ ((lane&7)<<4)) ^ (sk<<6)
  const int xorv  = (lane & 7) << 4;
  const int bcol0 = (l4 * 16) ^ xorv;
  int aoff[4], boff[4];
  #pragma unroll
  for (int i = 0; i < 4; ++i) {
    aoff[i] = (wr * 64 + i * 16 + l15) * 128 + bcol0;
    boff[i] = (wc * 64 + i * 16 + l15) * 128 + bcol0;
  }

  // per-lane row metadata: row = bm + wr*64 + mi*16 + l4*4 + r   (i = mi*4+r)
  float x2v[16]; int yv[16];
  #pragma unroll
  for (int i = 0; i < 16; ++i) {
    int row = bm + wr * 64 + (i >> 2) * 16 + l4 * 4 + (i & 3);
    x2v[i] = x2[row];
    yv[i]  = y[row];
  }
  float tot[16], mat[16];
  #pragma unroll
  for (int i = 0; i < 16; ++i) { tot[i] = 0.f; mat[i] = 0.f; }

  f32x4 accA[4][4], accB[4][4];
  float r2cP[4]; int clsP[4];

  // chunk pipeline: chunk 0 (no prev), chunk 1 (drains 0), then pairs; drain 7 after.
  chunk_body<false>(accA, accB, colstart + 0 * CHUNK, rbf, gA0, sA, sB, aoff, boff,
                    srow, scol, w, wc, l15, r2, yref, r2cP, clsP, x2v, yv, tot, mat);
  chunk_body<true >(accB, accA, colstart + 1 * CHUNK, rbf, gA0, sA, sB, aoff, boff,
                    srow, scol, w, wc, l15, r2, yref, r2cP, clsP, x2v, yv, tot, mat);
  for (int p = 1; p < NCHUNKS / 2; ++p) {
    chunk_body<true>(accA, accB, colstart + (2 * p) * CHUNK, rbf, gA0, sA, sB, aoff, boff,
                     srow, scol, w, wc, l15, r2, yref, r2cP, clsP, x2v, yv, tot, mat);
    chunk_body<true>(accB, accA, colstart + (2 * p + 1) * CHUNK, rbf, gA0, sA, sB, aoff, boff,
                     srow, scol, w, wc, l15, r2, yref, r2cP, clsP, x2v, yv, tot, mat);
  }

  // drain: epilogue of last chunk (odd -> lives in accB, metadata in r2cP/clsP)
  #pragma unroll
  for (int g = 0; g < 16; ++g) {
    const int mi = g >> 2, rr = g & 3;
    float xr = x2v[g];
    int   yy = yv[g];
    float tsum = 0.f, msum = 0.f;
    #pragma unroll
    for (int ni = 0; ni < 4; ++ni) {
      float t = fmaf(-2.0f, accB[mi][ni][rr], xr + r2cP[ni]);
      t = fmaxf(t, 0.0f);
      float d = __builtin_amdgcn_sqrtf(t);
      float e = __builtin_amdgcn_exp2f(-1.44269504088896f * d);
      tsum += e;
      msum += (clsP[ni] == yy) ? e : 0.0f;
    }
    tot[g] += tsum;
    mat[g] += msum;
  }

  // reduce across the 16 lanes (l15) that share each row, then merge globally
  #pragma unroll
  for (int i = 0; i < 16; ++i) {
    float t = tot[i], m = mat[i];
    #pragma unroll
    for (int d = 1; d <= 8; d <<= 1) {
      t += __shfl_xor(t, d, 64);
      m += __shfl_xor(m, d, 64);
    }
    if (l15 == 0) {
      int row = bm + wr * 64 + (i >> 2) * 16 + l4 * 4 + (i & 3);
      atomicAdd(&totG[row], t);
      atomicAdd(&matchG[row], m);
    }
  }
}

__global__ void finalize_loss(const float* __restrict__ totG, const float* __restrict__ matchG,
                              float* __restrict__ out) {
  __shared__ float red[256];
  int t = threadIdx.x;
  float s = 0.f;
  for (int r = t; r < M_ROWS; r += 256)
    s += logf(matchG[r] / totG[r] + 1e-6f);
  red[t] = s;
  __syncthreads();
  for (int off = 128; off >= 1; off >>= 1) {
    if (t < off) red[t] += red[t + off];
    __syncthreads();
  }
  if (t == 0) out[0] = -red[0] / (float)M_ROWS;
}

extern "C" void kernel_launch(void* const* d_in, const int* in_sizes, int n_in,
                              void* d_out, int out_size, void* d_ws, size_t ws_size,
                              hipStream_t stream) {
  const float* x    = (const float*)d_in[0];
  const float* xref = (const float*)d_in[1];
  const int*   y    = (const int*)d_in[2];
  const int*   yref = (const int*)d_in[3];
  float* out = (float*)d_out;

  uint8_t* ws = (uint8_t*)d_ws;
  uint16_t* xbf   = (uint16_t*)(ws);                    //  4 MB
  uint16_t* rbf   = (uint16_t*)(ws + 4194304);          // 32 MB
  float*    x2    = (float*)(ws + 37748736);            // 16 KB
  float*    r2    = (float*)(ws + 37765120);            // 128 KB
  float*    totG  = (float*)(ws + 37896192);            // 16 KB
  float*    matchG= (float*)(ws + 37912576);            // 16 KB

  hipMemsetAsync(totG, 0, 2 * M_ROWS * sizeof(float), stream);

  prep_rows<<<M_ROWS, 256, 0, stream>>>(x, xbf, x2);
  prep_rows<<<N_REFS, 256, 0, stream>>>(xref, rbf, r2);
  ask_main<<<dim3(M_ROWS / BM, NSPLIT), 256, 0, stream>>>(xbf, rbf, x2, r2, y, yref, totG, matchG);
  finalize_loss<<<1, 256, 0, stream>>>(totG, matchG, out);
}

// Round 5
// 246.150 us; speedup vs baseline: 1.6908x; 1.6908x over previous
//
#include <hip/hip_runtime.h>
#include <hip/hip_bf16.h>
#include <stdint.h>

#define M_ROWS 4096
#define N_REFS 32768
#define DIM    512
#define BM     256
#define BN     256
#define BK     32
#define NKT    (DIM / BK)          // 16 K-tiles
#define SETSZ  32768               // A 16KB + B 16KB per ring set
#define BOFF   16384

typedef __attribute__((ext_vector_type(8))) short short8;
typedef __attribute__((ext_vector_type(4))) float f32x4;

__device__ __forceinline__ uint32_t f2bf1(float f) {
  uint32_t u = __float_as_uint(f);
  return (u + 0x7FFFu + ((u >> 16) & 1u)) >> 16;   // RNE fp32 -> bf16
}

__global__ void prep_rows(const float* __restrict__ src, uint16_t* __restrict__ dst,
                          float* __restrict__ sq) {
  int row = blockIdx.x;
  int t = threadIdx.x;                       // 256 threads, 2 elems each
  const float2* s = (const float2*)(src + (size_t)row * DIM);
  float2 v = s[t];
  uint32_t packed = f2bf1(v.x) | (f2bf1(v.y) << 16);
  ((uint32_t*)(dst + (size_t)row * DIM))[t] = packed;
  float ss = v.x * v.x + v.y * v.y;
  #pragma unroll
  for (int d = 32; d >= 1; d >>= 1) ss += __shfl_down(ss, d, 64);
  __shared__ float wsum[4];
  int w = t >> 6, lane = t & 63;
  if (lane == 0) wsum[w] = ss;
  __syncthreads();
  if (t == 0) sq[row] = wsum[0] + wsum[1] + wsum[2] + wsum[3];
}

// 256x256 tile, 8 waves (2M x 4N), BK=32, ring-4 LDS double...quad buffer,
// counted vmcnt (steady state vmcnt(8) = 2 K-tiles in flight), 1 raw s_barrier
// per K-tile. T2 swizzle: LDS row = 64B, slot(l4,l15) = l4 ^ (l15&3) ^ (l15>>2)
// -> 2-way max bank aliasing (free). Staging deposits swizzled via pre-permuted
// global source column-group g(tid) (global_load_lds writes linearly, rule #21).
__global__ __launch_bounds__(512, 2) void ask_main(
    const uint16_t* __restrict__ xbf, const uint16_t* __restrict__ rbf,
    const float* __restrict__ x2, const float* __restrict__ r2,
    const int* __restrict__ y, const int* __restrict__ yref,
    float* __restrict__ totG, float* __restrict__ matchG)
{
  __shared__ unsigned char smem[4 * SETSZ];   // 128 KB

  const int tid  = threadIdx.x;
  const int w    = tid >> 6, lane = tid & 63;
  const int wr   = w >> 2,  wc   = w & 3;      // 2 x 4 wave grid
  const int l15  = lane & 15, l4 = lane >> 4;

  // XCD-aware swizzle (2048 % 8 == 0 -> simple form is bijective)
  const int wg    = blockIdx.x;
  const int swz   = (wg & 7) * 256 + (wg >> 3);
  const int mtile = swz >> 7, ntile = swz & 127;
  const int bm = mtile * BM, bn = ntile * BN;

  // ---- staging addresses (per-lane global, wave-uniform LDS) ----
  // LDS linear offset tid*16 <-> (row = tid>>2, slot = tid&3); source col-group
  // g = slot ^ (row&3) ^ ((row>>2)&3) so that a ds_read at slot l4^(l15&3)^(l15>>2)
  // returns k-group l4 for row base+l15.
  const int srow = tid >> 2;
  const int gsw  = (tid & 3) ^ ((tid >> 2) & 3) ^ ((tid >> 4) & 3);
  const uint16_t* gA = xbf + (size_t)(bm + srow) * DIM + gsw * 8;
  const uint16_t* gB = rbf + (size_t)(bn + srow) * DIM + gsw * 8;

#define GLL(srcp, dstoff)                                                        \
  __builtin_amdgcn_global_load_lds(                                              \
      (const __attribute__((address_space(1))) void*)(srcp),                     \
      (__attribute__((address_space(3))) void*)(smem + (dstoff)), 16, 0, 0)

  // ---- fragment read lane-bases (swizzled) ----
  const int slotr = l4 ^ (l15 & 3) ^ (l15 >> 2);
  const int aoffL = (wr * 128 + l15) * 64 + slotr * 16;          // + mf*1024
  const int boffL = BOFF + (wc * 64 + l15) * 64 + slotr * 16;    // + nf*1024

  f32x4 acc[8][4];
  const f32x4 fz = {0.f, 0.f, 0.f, 0.f};
  #pragma unroll
  for (int mf = 0; mf < 8; ++mf)
    #pragma unroll
    for (int nf = 0; nf < 4; ++nf) acc[mf][nf] = fz;

  // ---- prologue: stage tiles 0,1,2 (4 gll inst/wave each) ----
  #pragma unroll
  for (int tt = 0; tt < 3; ++tt) {
    GLL(gA + tt * BK,             tt * SETSZ + w * 1024);
    GLL(gA + tt * BK + 128 * DIM, tt * SETSZ + 8192 + w * 1024);
    GLL(gB + tt * BK,             tt * SETSZ + BOFF + w * 1024);
    GLL(gB + tt * BK + 128 * DIM, tt * SETSZ + BOFF + 8192 + w * 1024);
  }
  asm volatile("s_waitcnt vmcnt(8)" ::: "memory");   // tile 0 landed
  __builtin_amdgcn_s_barrier();

  const uint16_t* gAs = gA + 3 * BK;   // stage source for tile t+3
  const uint16_t* gBs = gB + 3 * BK;

  for (int t = 0; t < NKT; ++t) {
    const int set    = (t & 3) * SETSZ;
    const int sstage = ((t + 3) & 3) * SETSZ;
    const unsigned char* pA = smem + set + aoffL;
    const unsigned char* pB = smem + set + boffL;
    const bool dost = (t < NKT - 3);

    short8 bfr[4], afr[4];
    // -------- phase A: stage A(t+3) | read B all + A[0..3] | MFMA m0..3 --------
    if (dost) {
      GLL(gAs,             sstage + w * 1024);
      GLL(gAs + 128 * DIM, sstage + 8192 + w * 1024);
    }
    #pragma unroll
    for (int nf = 0; nf < 4; ++nf) bfr[nf] = *(const short8*)(pB + nf * 1024);
    #pragma unroll
    for (int mf = 0; mf < 4; ++mf) afr[mf] = *(const short8*)(pA + mf * 1024);
    __builtin_amdgcn_s_setprio(1);
    #pragma unroll
    for (int mf = 0; mf < 4; ++mf)
      #pragma unroll
      for (int nf = 0; nf < 4; ++nf)
        acc[mf][nf] = __builtin_amdgcn_mfma_f32_16x16x32_bf16(afr[mf], bfr[nf], acc[mf][nf], 0, 0, 0);
    __builtin_amdgcn_s_setprio(0);

    // -------- phase B: stage B(t+3) | read A[4..7] | MFMA m4..7 --------
    if (dost) {
      GLL(gBs,             sstage + BOFF + w * 1024);
      GLL(gBs + 128 * DIM, sstage + BOFF + 8192 + w * 1024);
    }
    #pragma unroll
    for (int mf = 0; mf < 4; ++mf) afr[mf] = *(const short8*)(pA + (mf + 4) * 1024);
    __builtin_amdgcn_s_setprio(1);
    #pragma unroll
    for (int mf = 0; mf < 4; ++mf)
      #pragma unroll
      for (int nf = 0; nf < 4; ++nf)
        acc[mf + 4][nf] = __builtin_amdgcn_mfma_f32_16x16x32_bf16(afr[mf], bfr[nf], acc[mf + 4][nf], 0, 0, 0);
    __builtin_amdgcn_s_setprio(0);

    // -------- boundary: tile t+1 must be resident; keep 2 tiles in flight --------
    if (t < NKT - 3)       { asm volatile("s_waitcnt vmcnt(8)" ::: "memory"); }
    else if (t == NKT - 3) { asm volatile("s_waitcnt vmcnt(4)" ::: "memory"); }
    else if (t == NKT - 2) { asm volatile("s_waitcnt vmcnt(0)" ::: "memory"); }
    if (t < NKT - 1) __builtin_amdgcn_s_barrier();
    gAs += BK; gBs += BK;
  }

  // ---- fused epilogue: e = exp(-sqrt(x2 + r2 - 2*dot)), per-row total/match ----
  float* redf = (float*)smem;          // [2 arr][256 rowlocal][4 wc] = 8 KB (set0 dead)
  #pragma unroll
  for (int mf = 0; mf < 8; ++mf) {
    const int growb = bm + wr * 128 + mf * 16 + l4 * 4;
    float x2r[4]; int yy[4];
    #pragma unroll
    for (int g = 0; g < 4; ++g) { x2r[g] = x2[growb + g]; yy[g] = y[growb + g]; }
    float tt[4] = {0.f, 0.f, 0.f, 0.f}, mm[4] = {0.f, 0.f, 0.f, 0.f};
    #pragma unroll
    for (int nf = 0; nf < 4; ++nf) {
      const int gcol = bn + wc * 64 + nf * 16 + l15;
      const float r2c = r2[gcol];
      const int   cls = yref[gcol];
      #pragma unroll
      for (int g = 0; g < 4; ++g) {
        float t2 = fmaf(-2.0f, acc[mf][nf][g], x2r[g] + r2c);
        t2 = fmaxf(t2, 0.0f);
        float d = __builtin_amdgcn_sqrtf(t2);
        float e = __builtin_amdgcn_exp2f(-1.44269504088896f * d);
        tt[g] += e;
        mm[g] += (cls == yy[g]) ? e : 0.0f;
      }
    }
    #pragma unroll
    for (int g = 0; g < 4; ++g) {
      float a = tt[g], b = mm[g];
      #pragma unroll
      for (int d = 1; d <= 8; d <<= 1) {
        a += __shfl_xor(a, d, 64);
        b += __shfl_xor(b, d, 64);
      }
      if (l15 == 0) {   // lanes 0,16,32,48 -> l4 = 0..3
        const int rl = wr * 128 + mf * 16 + l4 * 4 + g;
        redf[(0 * 256 + rl) * 4 + wc] = a;
        redf[(1 * 256 + rl) * 4 + wc] = b;
      }
    }
  }
  __syncthreads();
  {
    const int arr = tid >> 8, rl = tid & 255;       // 512 threads = 2 arrays x 256 rows
    const float* p = redf + (arr * 256 + rl) * 4;
    const float s = p[0] + p[1] + p[2] + p[3];
    atomicAdd((arr ? matchG : totG) + bm + rl, s);
  }
#undef GLL
}

__global__ void finalize_loss(const float* __restrict__ totG, const float* __restrict__ matchG,
                              float* __restrict__ out) {
  __shared__ float red[256];
  int t = threadIdx.x;
  float s = 0.f;
  for (int r = t; r < M_ROWS; r += 256)
    s += logf(matchG[r] / totG[r] + 1e-6f);
  red[t] = s;
  __syncthreads();
  for (int off = 128; off >= 1; off >>= 1) {
    if (t < off) red[t] += red[t + off];
    __syncthreads();
  }
  if (t == 0) out[0] = -red[0] / (float)M_ROWS;
}

extern "C" void kernel_launch(void* const* d_in, const int* in_sizes, int n_in,
                              void* d_out, int out_size, void* d_ws, size_t ws_size,
                              hipStream_t stream) {
  const float* x    = (const float*)d_in[0];
  const float* xref = (const float*)d_in[1];
  const int*   y    = (const int*)d_in[2];
  const int*   yref = (const int*)d_in[3];
  float* out = (float*)d_out;

  uint8_t* ws = (uint8_t*)d_ws;
  uint16_t* xbf   = (uint16_t*)(ws);                    //  4 MB
  uint16_t* rbf   = (uint16_t*)(ws + 4194304);          // 32 MB
  float*    x2    = (float*)(ws + 37748736);            // 16 KB
  float*    r2    = (float*)(ws + 37765120);            // 128 KB
  float*    totG  = (float*)(ws + 37896192);            // 16 KB
  float*    matchG= (float*)(ws + 37912576);            // 16 KB

  hipMemsetAsync(totG, 0, 2 * M_ROWS * sizeof(float), stream);

  prep_rows<<<M_ROWS, 256, 0, stream>>>(x, xbf, x2);
  prep_rows<<<N_REFS, 256, 0, stream>>>(xref, rbf, r2);
  ask_main<<<(M_ROWS / BM) * (N_REFS / BN), 512, 0, stream>>>(xbf, rbf, x2, r2, y, yref, totG, matchG);
  finalize_loss<<<1, 256, 0, stream>>>(totG, matchG, out);
}

// Round 6
// 229.345 us; speedup vs baseline: 1.8147x; 1.0733x over previous
//
#include <hip/hip_runtime.h>
#include <hip/hip_bf16.h>
#include <stdint.h>

#define M_ROWS 4096
#define N_REFS 32768
#define DIM    512
#define BM     256
#define BN     128
#define BK     64
#define NKT    (DIM / BK)          // 8 K-tiles
#define SETA   32768               // A: 256 rows x 128B
#define SETB   16384               // B: 128 rows x 128B
#define SETSZ  (SETA + SETB)       // 48 KB per ring set
#define NTILE  (N_REFS / BN)       // 256
#define MTILE  (M_ROWS / BM)       // 16

typedef __attribute__((ext_vector_type(8))) short short8;
typedef __attribute__((ext_vector_type(4))) float f32x4;

__device__ __forceinline__ uint32_t f2bf1(float f) {
  uint32_t u = __float_as_uint(f);
  return (u + 0x7FFFu + ((u >> 16) & 1u)) >> 16;   // RNE fp32 -> bf16
}

__global__ void prep_rows(const float* __restrict__ src, uint16_t* __restrict__ dst,
                          float* __restrict__ sq) {
  int row = blockIdx.x;
  int t = threadIdx.x;                       // 256 threads, 2 elems each
  const float2* s = (const float2*)(src + (size_t)row * DIM);
  float2 v = s[t];
  uint32_t packed = f2bf1(v.x) | (f2bf1(v.y) << 16);
  ((uint32_t*)(dst + (size_t)row * DIM))[t] = packed;
  float ss = v.x * v.x + v.y * v.y;
  #pragma unroll
  for (int d = 32; d >= 1; d >>= 1) ss += __shfl_down(ss, d, 64);
  __shared__ float wsum[4];
  int w = t >> 6, lane = t & 63;
  if (lane == 0) wsum[w] = ss;
  __syncthreads();
  if (t == 0) sq[row] = wsum[0] + wsum[1] + wsum[2] + wsum[3];
}

// 256x128 tile, 8 waves (4M x 2N, per-wave 64x64 = R3's verified fragment
// geometry), BK=64 (128B LDS rows -> R3's zero-conflict swizzle), RING-3 LDS
// (48KB x 3 = 144KB) so 2 K-tiles stay in flight. Counted vmcnt(6) + one raw
// s_barrier per K-tile; setprio around MFMA clusters (T5). Staging deposits
// linearly; read applies slot ^= (l15&7); source column pre-permuted by the
// same involution (rule #21).
__global__ __launch_bounds__(512, 2) void ask_main(
    const uint16_t* __restrict__ xbf, const uint16_t* __restrict__ rbf,
    const float* __restrict__ x2, const float* __restrict__ r2,
    const int* __restrict__ y, const int* __restrict__ yref,
    float* __restrict__ totG, float* __restrict__ matchG)
{
  __shared__ unsigned char smem[3 * SETSZ];   // 144 KB

  const int tid  = threadIdx.x;
  const int w    = tid >> 6, lane = tid & 63;
  const int wr   = w >> 1,  wc   = w & 1;      // 4 x 2 wave grid
  const int l15  = lane & 15, l4 = lane >> 4;

  // XCD-aware swizzle: nwg = 4096, 4096 % 8 == 0 -> simple form bijective.
  // Within an XCD chunk ntile varies fastest -> A-tile stays L2-resident.
  const int wg    = blockIdx.x;
  const int swz   = (wg & 7) * 512 + (wg >> 3);
  const int mtile = swz >> 8, ntile = swz & 255;
  const int bm = mtile * BM, bn = ntile * BN;

  // ---- staging: thread tid covers (row = c*64 + tid>>3, slot = tid&7) ----
  // LDS write is linear (chunk*8192 + tid*16); read XORs slot with (row&7),
  // so source col-group = (tid&7) ^ ((tid>>3)&7).
  const int strow = tid >> 3;                         // 0..63
  const int sgsw  = ((tid & 7) ^ (strow & 7)) * 8;    // pre-swizzled col elems
  const uint16_t* aBase = xbf + (size_t)(bm + strow) * DIM + sgsw;
  const uint16_t* bBase = rbf + (size_t)(bn + strow) * DIM + sgsw;

#define GLL(srcp, dstoff)                                                        \
  __builtin_amdgcn_global_load_lds(                                              \
      (const __attribute__((address_space(1))) void*)(srcp),                     \
      (__attribute__((address_space(3))) void*)(smem + (dstoff)), 16, 0, 0)

  // stage tile kt into ring set s: A chunks c0..3 (rows c*64..), B chunks c0..1
#define STAGE_P0(kt, s)                                                          \
  GLL(aBase + (kt) * BK,                 (s) * SETSZ + 0 * 8192 + tid * 16);     \
  GLL(aBase + (kt) * BK + 1 * 64 * DIM,  (s) * SETSZ + 1 * 8192 + tid * 16);     \
  GLL(bBase + (kt) * BK,                 (s) * SETSZ + SETA + 0 * 8192 + tid * 16)
#define STAGE_P1(kt, s)                                                          \
  GLL(aBase + (kt) * BK + 2 * 64 * DIM,  (s) * SETSZ + 2 * 8192 + tid * 16);     \
  GLL(aBase + (kt) * BK + 3 * 64 * DIM,  (s) * SETSZ + 3 * 8192 + tid * 16);     \
  GLL(bBase + (kt) * BK + 1 * 64 * DIM,  (s) * SETSZ + SETA + 1 * 8192 + tid * 16)

  // ---- fragment read lane-bases ----
  // A row = wr*64 + mf*16 + l15 ; byte = row*128 + slot(ks)*16,
  // slot(ks) = ((ks<<2)|l4) ^ (l15&7)  [row&7 == l15&7].
  const int slot0 = (l4 ^ (l15 & 7)) * 16;
  const int slot1 = ((4 | l4) ^ (l15 & 7)) * 16;
  const int aRow  = (wr * 64 + l15) * 128;            // + mf*2048
  const int bRow  = SETA + (wc * 64 + l15) * 128;     // + nf*2048

  f32x4 acc[4][4];
  const f32x4 fz = {0.f, 0.f, 0.f, 0.f};
  #pragma unroll
  for (int mf = 0; mf < 4; ++mf)
    #pragma unroll
    for (int nf = 0; nf < 4; ++nf) acc[mf][nf] = fz;

  // ---- prologue: stage tiles 0 and 1 ----
  STAGE_P0(0, 0); STAGE_P1(0, 0);
  STAGE_P0(1, 1); STAGE_P1(1, 1);
  asm volatile("s_waitcnt vmcnt(6)" ::: "memory");    // tile 0 landed (own share)
  __builtin_amdgcn_s_barrier();

  #pragma unroll
  for (int t = 0; t < NKT; ++t) {
    const int set    = t % 3;
    const int sstage = (t + 2) % 3;
    const unsigned char* pA = smem + set * SETSZ + aRow;
    const unsigned char* pB = smem + set * SETSZ + bRow;

    short8 afr[4], bfr[4];
    // -------- phase 0 (ks=0): stage 3 | read 8 | MFMA 16 --------
    if (t + 2 < NKT) { STAGE_P0(t + 2, sstage); }
    #pragma unroll
    for (int nf = 0; nf < 4; ++nf) bfr[nf] = *(const short8*)(pB + nf * 2048 + slot0);
    #pragma unroll
    for (int mf = 0; mf < 4; ++mf) afr[mf] = *(const short8*)(pA + mf * 2048 + slot0);
    __builtin_amdgcn_s_setprio(1);
    #pragma unroll
    for (int mf = 0; mf < 4; ++mf)
      #pragma unroll
      for (int nf = 0; nf < 4; ++nf)
        acc[mf][nf] = __builtin_amdgcn_mfma_f32_16x16x32_bf16(afr[mf], bfr[nf], acc[mf][nf], 0, 0, 0);
    __builtin_amdgcn_s_setprio(0);

    // -------- phase 1 (ks=1): stage 3 | read 8 | MFMA 16 --------
    if (t + 2 < NKT) { STAGE_P1(t + 2, sstage); }
    #pragma unroll
    for (int nf = 0; nf < 4; ++nf) bfr[nf] = *(const short8*)(pB + nf * 2048 + slot1);
    #pragma unroll
    for (int mf = 0; mf < 4; ++mf) afr[mf] = *(const short8*)(pA + mf * 2048 + slot1);
    __builtin_amdgcn_s_setprio(1);
    #pragma unroll
    for (int mf = 0; mf < 4; ++mf)
      #pragma unroll
      for (int nf = 0; nf < 4; ++nf)
        acc[mf][nf] = __builtin_amdgcn_mfma_f32_16x16x32_bf16(afr[mf], bfr[nf], acc[mf][nf], 0, 0, 0);
    __builtin_amdgcn_s_setprio(0);

    // -------- boundary: next tile must be resident; keep ring full --------
    if (t < NKT - 2)      { asm volatile("s_waitcnt vmcnt(6)" ::: "memory"); }
    else if (t == NKT - 2){ asm volatile("s_waitcnt vmcnt(0)" ::: "memory"); }
    if (t < NKT - 1) __builtin_amdgcn_s_barrier();
  }

  // ---- fused epilogue: e = exp(-sqrt(x2 + r2 - 2*dot)), per-row total/match ----
  __syncthreads();                       // drain everything; smem reused below
  float* redf = (float*)smem;            // [2 arr][256 rowlocal][2 wc] = 4 KB
  #pragma unroll
  for (int mf = 0; mf < 4; ++mf) {
    const int growb = bm + wr * 64 + mf * 16 + l4 * 4;
    float x2r[4]; int yy[4];
    #pragma unroll
    for (int g = 0; g < 4; ++g) { x2r[g] = x2[growb + g]; yy[g] = y[growb + g]; }
    float tt[4] = {0.f, 0.f, 0.f, 0.f}, mm[4] = {0.f, 0.f, 0.f, 0.f};
    #pragma unroll
    for (int nf = 0; nf < 4; ++nf) {
      const int gcol = bn + wc * 64 + nf * 16 + l15;
      const float r2c = r2[gcol];
      const int   cls = yref[gcol];
      #pragma unroll
      for (int g = 0; g < 4; ++g) {
        float t2 = fmaf(-2.0f, acc[mf][nf][g], x2r[g] + r2c);
        t2 = fmaxf(t2, 0.0f);
        float d = __builtin_amdgcn_sqrtf(t2);
        float e = __builtin_amdgcn_exp2f(-1.44269504088896f * d);
        tt[g] += e;
        mm[g] += (cls == yy[g]) ? e : 0.0f;
      }
    }
    #pragma unroll
    for (int g = 0; g < 4; ++g) {
      float a = tt[g], b = mm[g];
      #pragma unroll
      for (int d = 1; d <= 8; d <<= 1) {
        a += __shfl_xor(a, d, 64);
        b += __shfl_xor(b, d, 64);
      }
      if (l15 == 0) {   // lanes 0,16,32,48 -> l4 = 0..3
        const int rl = wr * 64 + mf * 16 + l4 * 4 + g;
        redf[(0 * 256 + rl) * 2 + wc] = a;
        redf[(1 * 256 + rl) * 2 + wc] = b;
      }
    }
  }
  __syncthreads();
  {
    const int arr = tid >> 8, rl = tid & 255;       // 512 threads = 2 arrays x 256 rows
    const float* p = redf + (arr * 256 + rl) * 2;
    const float s = p[0] + p[1];
    atomicAdd((arr ? matchG : totG) + bm + rl, s);
  }
#undef GLL
#undef STAGE_P0
#undef STAGE_P1
}

__global__ void finalize_loss(const float* __restrict__ totG, const float* __restrict__ matchG,
                              float* __restrict__ out) {
  __shared__ float red[256];
  int t = threadIdx.x;
  float s = 0.f;
  for (int r = t; r < M_ROWS; r += 256)
    s += logf(matchG[r] / totG[r] + 1e-6f);
  red[t] = s;
  __syncthreads();
  for (int off = 128; off >= 1; off >>= 1) {
    if (t < off) red[t] += red[t + off];
    __syncthreads();
  }
  if (t == 0) out[0] = -red[0] / (float)M_ROWS;
}

extern "C" void kernel_launch(void* const* d_in, const int* in_sizes, int n_in,
                              void* d_out, int out_size, void* d_ws, size_t ws_size,
                              hipStream_t stream) {
  const float* x    = (const float*)d_in[0];
  const float* xref = (const float*)d_in[1];
  const int*   y    = (const int*)d_in[2];
  const int*   yref = (const int*)d_in[3];
  float* out = (float*)d_out;

  uint8_t* ws = (uint8_t*)d_ws;
  uint16_t* xbf   = (uint16_t*)(ws);                    //  4 MB
  uint16_t* rbf   = (uint16_t*)(ws + 4194304);          // 32 MB
  float*    x2    = (float*)(ws + 37748736);            // 16 KB
  float*    r2    = (float*)(ws + 37765120);            // 128 KB
  float*    totG  = (float*)(ws + 37896192);            // 16 KB
  float*    matchG= (float*)(ws + 37912576);            // 16 KB

  hipMemsetAsync(totG, 0, 2 * M_ROWS * sizeof(float), stream);

  prep_rows<<<M_ROWS, 256, 0, stream>>>(x, xbf, x2);
  prep_rows<<<N_REFS, 256, 0, stream>>>(xref, rbf, r2);
  ask_main<<<MTILE * NTILE, 512, 0, stream>>>(xbf, rbf, x2, r2, y, yref, totG, matchG);
  finalize_loss<<<1, 256, 0, stream>>>(totG, matchG, out);
}